// Round 12
// baseline (273.016 us; speedup 1.0000x reference)
//
#include <hip/hip_runtime.h>
#include <hip/hip_bf16.h>

#define NAG 256
#define HID 128
#define ACT 5
#define NH 4
#define DD 144      // concat dim
#define EE 576      // embed dim
#define HDIM 144    // per-head dim
#define CMAX 20     // fast-path neighbor cap (expected c ~ 4-8)

// ---------------------------------------------------------------------------
// prep: C[i,:] = concat(hidden[i,:] @ W_enc + b_enc, action[i,:])  [256 x 144]
// grid 256, block 128.
// ---------------------------------------------------------------------------
__global__ __launch_bounds__(128) void k_prep(
    const float* __restrict__ hidden, const float* __restrict__ action,
    const float* __restrict__ W_enc, const float* __restrict__ b_enc,
    float* __restrict__ C)
{
    __shared__ float hrow[HID];
    __shared__ float part[8][16];
    const int i = blockIdx.x, t = threadIdx.x;
    hrow[t] = hidden[i * HID + t];
    __syncthreads();
    const int o = t & 15, pr = t >> 4;
    float p = 0.f;
    for (int d = pr * 16; d < pr * 16 + 16; ++d)
        p += hrow[d] * W_enc[d * 16 + o];
    part[pr][o] = p;
    __syncthreads();
    if (t < 16) {
        float s = 0.f;
        for (int pp = 0; pp < 8; ++pp) s += part[pp][t];
        C[i * DD + t] = s + b_enc[t];
    }
    C[i * DD + 16 + t] = action[i * HID + t];
}

// ---------------------------------------------------------------------------
// LDS-tiled GEMM (canonical): out[z][256 x N] = A[z][256 x K] @ W[z][K x N]
//   (+ bscale[row] * b[z][col]).
// Tile: 32 rows x 64 cols, 256 threads, thread = 2 rows x 4 cols.
// K chunks of 64 staged in LDS: A k-major (stride 34), W row-major (stride 68)
// -> compute reads are broadcast/2-way conflict-free ds_read_b64/b128.
// Register prefetch of chunk i+1 overlaps compute of chunk i.
// XCD swizzle: all 8 mb-tiles of one (bx,z) weight strip share an XCD's L2.
// grid = 8 * 8 * ceil(G/8); no early exit after first barrier.
// ---------------------------------------------------------------------------
template<int K, int NX, int G>
__global__ __launch_bounds__(256) void k_gemmT(
    const float* __restrict__ A0, const float* __restrict__ A1, const float* __restrict__ A2,
    const float* __restrict__ W0, const float* __restrict__ W1, const float* __restrict__ W2,
    const float* __restrict__ bb0, const float* __restrict__ bb1, const float* __restrict__ bb2,
    const float* __restrict__ bscale,
    float* __restrict__ o0, float* __restrict__ o1, float* __restrict__ o2,
    int N)
{
    const int p = blockIdx.x;
    const int xcd = p & 7, slot = p >> 3;
    const int mb = slot & 7, gslot = slot >> 3;
    const int g = xcd + 8 * gslot;          // block-uniform
    if (g >= G) return;                     // before any barrier: safe
    const int bx = g % NX, z = g / NX;
    const float* A   = (z == 0) ? A0  : (z == 1) ? A1  : A2;
    const float* W   = (z == 0) ? W0  : (z == 1) ? W1  : W2;
    const float* bia = (z == 0) ? bb0 : (z == 1) ? bb1 : bb2;
    float*       out = (z == 0) ? o0  : (z == 1) ? o1  : o2;

    __shared__ float As[64 * 34];           // [k][row], stride 34 (8B-aligned b64)
    __shared__ float Ws[64 * 68];           // [k][col], stride 68 (16B-aligned b128)
    const int tid = threadIdx.x;
    const int tc = tid & 15, tr = tid >> 4;
    const int row0 = mb * 32 + tr * 2;
    const int col  = bx * 64 + tc * 4;
    float acc[2][4] = {{0.f,0.f,0.f,0.f},{0.f,0.f,0.f,0.f}};

    float4 ra[2], rw[4];
    // prefetch chunk 0
    {
        const int Kc = (K < 64) ? K : 64;
        #pragma unroll
        for (int qd = 0; qd < 2; ++qd) {
            int idx = tid + 256 * qd, rr = idx >> 4, kq = idx & 15;
            if (kq * 4 < Kc)
                ra[qd] = *(const float4*)(A + (size_t)(mb * 32 + rr) * K + kq * 4);
        }
        #pragma unroll
        for (int qd = 0; qd < 4; ++qd) {
            int idx = tid + 256 * qd, kk = idx >> 4, cq = idx & 15;
            int cc = bx * 64 + cq * 4;
            if (kk < Kc && cc < N)
                rw[qd] = *(const float4*)(W + (size_t)kk * N + cc);
        }
    }
    const int nch = (K + 63) / 64;
    for (int ci = 0; ci < nch; ++ci) {
        const int k0 = ci * 64;
        const int Kc = (K - k0 < 64) ? (K - k0) : 64;
        __syncthreads();                    // prior compute done, LDS reusable
        #pragma unroll
        for (int qd = 0; qd < 2; ++qd) {    // A -> LDS (k-major transpose)
            int idx = tid + 256 * qd, rr = idx >> 4, kq = idx & 15;
            if (kq * 4 < Kc) {
                As[(kq * 4 + 0) * 34 + rr] = ra[qd].x;
                As[(kq * 4 + 1) * 34 + rr] = ra[qd].y;
                As[(kq * 4 + 2) * 34 + rr] = ra[qd].z;
                As[(kq * 4 + 3) * 34 + rr] = ra[qd].w;
            }
        }
        #pragma unroll
        for (int qd = 0; qd < 4; ++qd) {    // W -> LDS
            int idx = tid + 256 * qd, kk = idx >> 4, cq = idx & 15;
            int cc = bx * 64 + cq * 4;
            if (kk < Kc && cc < N)
                *((float4*)&Ws[kk * 68 + cq * 4]) = rw[qd];
        }
        __syncthreads();
        if (ci + 1 < nch) {                 // prefetch next chunk (overlaps compute)
            const int k0n = k0 + 64;
            const int Kcn = (K - k0n < 64) ? (K - k0n) : 64;
            #pragma unroll
            for (int qd = 0; qd < 2; ++qd) {
                int idx = tid + 256 * qd, rr = idx >> 4, kq = idx & 15;
                if (kq * 4 < Kcn)
                    ra[qd] = *(const float4*)(A + (size_t)(mb * 32 + rr) * K + k0n + kq * 4);
            }
            #pragma unroll
            for (int qd = 0; qd < 4; ++qd) {
                int idx = tid + 256 * qd, kk = idx >> 4, cq = idx & 15;
                int cc = bx * 64 + cq * 4;
                if (kk < Kcn && cc < N)
                    rw[qd] = *(const float4*)(W + (size_t)(k0n + kk) * N + cc);
            }
        }
        if (Kc == 64) {
            #pragma unroll 16
            for (int k = 0; k < 64; ++k) {
                float2 a2 = *(const float2*)&As[k * 34 + tr * 2];
                float4 w4 = *(const float4*)&Ws[k * 68 + tc * 4];
                acc[0][0] += a2.x * w4.x; acc[0][1] += a2.x * w4.y;
                acc[0][2] += a2.x * w4.z; acc[0][3] += a2.x * w4.w;
                acc[1][0] += a2.y * w4.x; acc[1][1] += a2.y * w4.y;
                acc[1][2] += a2.y * w4.z; acc[1][3] += a2.y * w4.w;
            }
        } else {
            for (int k = 0; k < Kc; ++k) {
                float2 a2 = *(const float2*)&As[k * 34 + tr * 2];
                float4 w4 = *(const float4*)&Ws[k * 68 + tc * 4];
                acc[0][0] += a2.x * w4.x; acc[0][1] += a2.x * w4.y;
                acc[0][2] += a2.x * w4.z; acc[0][3] += a2.x * w4.w;
                acc[1][0] += a2.y * w4.x; acc[1][1] += a2.y * w4.y;
                acc[1][2] += a2.y * w4.z; acc[1][3] += a2.y * w4.w;
            }
        }
    }
    if (col < N) {
        #pragma unroll
        for (int r2 = 0; r2 < 2; ++r2) {
            const int row = row0 + r2;
            float bs = bscale ? bscale[row] : 1.f;
            float4 o4;
            o4.x = acc[r2][0] + (bia ? bs * bia[col + 0] : 0.f);
            o4.y = acc[r2][1] + (bia ? bs * bia[col + 1] : 0.f);
            o4.z = acc[r2][2] + (bia ? bs * bia[col + 2] : 0.f);
            o4.w = acc[r2][3] + (bia ? bs * bia[col + 3] : 0.f);
            *((float4*)(out + (size_t)row * N + col)) = o4;
        }
    }
}

// ---------------------------------------------------------------------------
// Fused scores + attention reduction (proven rounds 8/10/11).
// ---------------------------------------------------------------------------
__global__ __launch_bounds__(256) void k_attn(
    const int* __restrict__ state, const float* __restrict__ q,
    const float* __restrict__ kmat, const float* __restrict__ v,
    float* __restrict__ ctxsum, float* __restrict__ cnt)
{
    __shared__ int lst[NAG];
    __shared__ int cnt_s;
    __shared__ float w4[NH][NAG];
    __shared__ float qh[CMAX][HDIM + 1];
    __shared__ float kh[CMAX][HDIM + 1];
    __shared__ float Sl[CMAX][CMAX + 1];
    const int i = blockIdx.x, tid = threadIdx.x;
    if (tid == 0) cnt_s = 0;
    __syncthreads();
    {
        int xi = state[2 * i], yi = state[2 * i + 1];
        int xj = state[2 * tid], yj = state[2 * tid + 1];
        int dx = xi - xj; if (dx < 0) dx = -dx;
        int dy = yi - yj; if (dy < 0) dy = -dy;
        if (tid > i && dx <= 4 && dy <= 2) {
            int p = atomicAdd(&cnt_s, 1);
            lst[p] = tid;
        }
    }
    __syncthreads();
    const int c = cnt_s;                 // block-uniform
    if (tid == 0) cnt[i] = (float)c;
    if (c == 0) {
        for (int e = tid; e < EE; e += 256) ctxsum[i * EE + e] = 0.f;
        return;
    }
    if (c <= CMAX) {
        for (int h = 0; h < NH; ++h) {
            for (int idx = tid; idx < c * HDIM; idx += 256) {
                int jj = idx / HDIM, d = idx % HDIM;
                qh[jj][d] = q[lst[jj] * EE + h * HDIM + d];
                kh[jj][d] = kmat[lst[jj] * EE + h * HDIM + d];
            }
            __syncthreads();
            for (int pp = tid; pp < c * c; pp += 256) {
                int jj = pp / c, kk = pp % c;
                float acc = 0.f;
                for (int d = 0; d < HDIM; ++d) acc += qh[jj][d] * kh[kk][d];
                Sl[jj][kk] = acc * (1.0f / 12.0f);
            }
            __syncthreads();
            if (tid < c) {
                float m = -1e30f;
                for (int kk = 0; kk < c; ++kk) m = fmaxf(m, Sl[tid][kk]);
                float zz = 0.f;
                for (int kk = 0; kk < c; ++kk) zz += __expf(Sl[tid][kk] - m);
                float inv = 1.f / fmaxf(zz, 1e-9f);
                for (int kk = 0; kk < c; ++kk)
                    Sl[tid][kk] = __expf(Sl[tid][kk] - m) * inv;
            }
            __syncthreads();
            if (tid < c) {
                float s = 0.f;
                for (int jj = 0; jj < c; ++jj) s += Sl[jj][tid];
                w4[h][tid] = s;
            }
            __syncthreads();
        }
    } else {
        for (int idx = tid; idx < NH * c; idx += 256) w4[idx / c][idx % c] = 0.f;
        __syncthreads();
        for (int pnh = tid; pnh < NH * c; pnh += 256) {
            int h = pnh / c, jj = pnh % c;
            const float* qrow = q + lst[jj] * EE + h * HDIM;
            float m = -1e30f;
            for (int kk = 0; kk < c; ++kk) {
                const float* krow = kmat + lst[kk] * EE + h * HDIM;
                float a = 0.f;
                for (int d = 0; d < HDIM; ++d) a += qrow[d] * krow[d];
                m = fmaxf(m, a * (1.0f / 12.0f));
            }
            float zz = 0.f;
            for (int kk = 0; kk < c; ++kk) {
                const float* krow = kmat + lst[kk] * EE + h * HDIM;
                float a = 0.f;
                for (int d = 0; d < HDIM; ++d) a += qrow[d] * krow[d];
                zz += __expf(a * (1.0f / 12.0f) - m);
            }
            float inv = 1.f / fmaxf(zz, 1e-9f);
            for (int kk = 0; kk < c; ++kk) {
                const float* krow = kmat + lst[kk] * EE + h * HDIM;
                float a = 0.f;
                for (int d = 0; d < HDIM; ++d) a += qrow[d] * krow[d];
                atomicAdd(&w4[h][kk], __expf(a * (1.0f / 12.0f) - m) * inv);
            }
        }
        __syncthreads();
    }
    for (int e = tid; e < EE; e += 256) {
        int h = e / HDIM;
        float acc = 0.f;
        for (int t = 0; t < c; ++t) acc += w4[h][t] * v[lst[t] * EE + e];
        ctxsum[i * EE + e] = acc;
    }
}

// ---------------------------------------------------------------------------
// Dueling head: per agent i (block, 64 threads).
// ---------------------------------------------------------------------------
__global__ __launch_bounds__(64) void k_head(
    const float* __restrict__ h,
    const float* __restrict__ W_val, const float* __restrict__ b_val,
    const float* __restrict__ W_adv, const float* __restrict__ b_adv,
    float* __restrict__ out)
{
    const int i = blockIdx.x, t = threadIdx.x;
    const float* hr = h + i * DD;
    float h0 = hr[t], h1 = hr[t + 64];
    float h2 = (t < 16) ? hr[t + 128] : 0.f;
    float red[6];
    for (int o = 0; o < 6; ++o) {
        float p;
        if (o < 5) {
            p = h0 * W_adv[t * ACT + o] + h1 * W_adv[(t + 64) * ACT + o];
            if (t < 16) p += h2 * W_adv[(t + 128) * ACT + o];
        } else {
            p = h0 * W_val[t] + h1 * W_val[t + 64];
            if (t < 16) p += h2 * W_val[t + 128];
        }
        for (int off = 32; off; off >>= 1) p += __shfl_xor(p, off);
        red[o] = p;
    }
    if (t == 0) {
        float a[ACT], mean = 0.f;
        for (int o = 0; o < ACT; ++o) { a[o] = red[o] + b_adv[o]; mean += a[o]; }
        mean *= (1.0f / ACT);
        float V = red[5] + b_val[0];
        for (int o = 0; o < ACT; ++o) out[i * ACT + o] = V + a[o] - mean;
    }
}

// ---------------------------------------------------------------------------
extern "C" void kernel_launch(void* const* d_in, const int* in_sizes, int n_in,
                              void* d_out, int out_size, void* d_ws, size_t ws_size,
                              hipStream_t stream)
{
    const float* hidden = (const float*)d_in[0];
    const float* action = (const float*)d_in[1];
    const int*   state  = (const int*)d_in[2];

    float* ws = (float*)d_ws;
    float* C    = ws;                        // 256*144
    float* tq   = C   + NAG * DD;            // 256*576 each
    float* tk   = tq  + NAG * EE;
    float* tv   = tk  + NAG * EE;
    float* q    = tv  + NAG * EE;
    float* kbuf = q   + NAG * EE;
    float* v    = kbuf+ NAG * EE;
    float* ctx  = v   + NAG * EE;
    float* cnt  = ctx + NAG * EE;            // 256
    // aliases: tq,tk dead after gemm2
    float* tout = tq;
    float* hbuf = tk;
    // total ws use ~4.3 MB (round-11 proven >= 5.9 MB)

    // prep: C = concat(enc(hidden), action)
    k_prep<<<NAG, 128, 0, stream>>>(hidden, action,
        (const float*)d_in[3], (const float*)d_in[4], C);

    // gemm1: t_{q,k,v} = C @ {Wq,Wk,Wv} + b   (K=144, N=576, G=27)
    k_gemmT<144, 9, 27><<<256, 256, 0, stream>>>(C, C, C,
        (const float*)d_in[5], (const float*)d_in[7], (const float*)d_in[9],
        (const float*)d_in[6], (const float*)d_in[8], (const float*)d_in[10],
        nullptr, tq, tk, tv, EE);

    // gemm2: {q,k,v} = t @ {Wiq,Wik,Wiv} + bi   (K=576, N=576, G=27)
    k_gemmT<576, 9, 27><<<256, 256, 0, stream>>>(tq, tk, tv,
        (const float*)d_in[11], (const float*)d_in[13], (const float*)d_in[15],
        (const float*)d_in[12], (const float*)d_in[14], (const float*)d_in[16],
        nullptr, q, kbuf, v, EE);

    // fused scores+attention
    k_attn<<<NAG, 256, 0, stream>>>(state, q, kbuf, v, ctx, cnt);

    // gemm3: tout = ctx @ Wo + cnt*bo   (K=576, N=576, G=9)
    k_gemmT<576, 9, 9><<<128, 256, 0, stream>>>(ctx, ctx, ctx,
        (const float*)d_in[17], (const float*)d_in[17], (const float*)d_in[17],
        (const float*)d_in[18], (const float*)d_in[18], (const float*)d_in[18],
        cnt, tout, tout, tout, EE);

    // gemm4: hbuf = tout @ W_O   (K=576, N=144, G=3, no bias)
    k_gemmT<576, 3, 3><<<64, 256, 0, stream>>>(tout, tout, tout,
        (const float*)d_in[19], (const float*)d_in[19], (const float*)d_in[19],
        nullptr, nullptr, nullptr,
        nullptr, hbuf, hbuf, hbuf, DD);

    k_head<<<NAG, 64, 0, stream>>>(hbuf,
        (const float*)d_in[20], (const float*)d_in[21],
        (const float*)d_in[22], (const float*)d_in[23], (float*)d_out);
}